// Round 7
// baseline (3607.431 us; speedup 1.0000x reference)
//
#include <hip/hip_runtime.h>
#include <math.h>

#define H 300
#define H3 900
#define NAt 16385
#define NBd 65537
#define NM 256
#define APM 64

typedef __attribute__((ext_vector_type(8))) short bf16x8;
typedef __attribute__((ext_vector_type(4))) float f32x4;

__device__ __forceinline__ unsigned bf16_rne(float x) {
  unsigned u = __float_as_uint(x);
  return (u + 0x7fffu + ((u >> 16) & 1u)) >> 16;
}
__device__ __forceinline__ float bf16_up(unsigned h) {
  return __uint_as_float(h << 16);
}
// 3-way split: x ~= h + m + l (each bf16), residual ~2^-26 |x|
__device__ __forceinline__ void split3(float x, unsigned &h, unsigned &m, unsigned &l) {
  h = bf16_rne(x);
  float r1 = x - bf16_up(h);
  m = bf16_rne(r1);
  float r2 = r1 - bf16_up(m);
  l = bf16_rne(r2);
}
__device__ __forceinline__ void pack8(const unsigned* v, uint4 &o) {
  o.x = v[0] | (v[1] << 16); o.y = v[2] | (v[3] << 16);
  o.z = v[4] | (v[5] << 16); o.w = v[6] | (v[7] << 16);
}

// ======================= weight pre-split =======================
template<bool TRANS>
__global__ __launch_bounds__(256) void prep_split_kernel(
    const float* __restrict__ B, uint4* __restrict__ out,
    int K, int N, int ldb, int KT, int NT)
{
  int g = blockIdx.x * 256 + threadIdx.x;
  int total = KT * NT * 64;
  if (g >= total) return;
  int lane = g & 63;
  int t = (g >> 6) % NT;
  int kt = (g >> 6) / NT;
  int n = t * 16 + (lane & 15);
  int kb = kt * 32 + ((lane >> 4) << 3);
  float x[8];
#pragma unroll
  for (int j = 0; j < 8; j++) {
    int gk = kb + j;
    float v = 0.f;
    if (n < N && gk < K)
      v = TRANS ? B[(size_t)n * ldb + gk] : B[(size_t)gk * ldb + n];
    x[j] = v;
  }
  unsigned h[8], m[8], l[8];
#pragma unroll
  for (int j = 0; j < 8; j++) split3(x[j], h[j], m[j], l[j]);
  uint4 hv, mv, lv;
  pack8(h, hv); pack8(m, mv); pack8(l, lv);
  out[g] = hv;
  out[total + g] = mv;
  out[2 * total + g] = lv;
}

// ============== split-bf16 MFMA GEMM (EXACT r12 — proven 2763us total) ==============
// r16: GEMM microstructure declared at plateau (r12/r14/r15 all 155-190us);
// reverted to r12 verbatim. This round attacks the GRU launch chain instead.
template<bool ADDMAT, bool BIAS, bool RELU, bool GATHER, bool CONCAT, bool W2, bool VEC>
__global__ __launch_bounds__(256, 2) void gemm_mfma3(
    const float* __restrict__ A, const float* __restrict__ A2,
    const float* __restrict__ A3,
    const int* __restrict__ idx1, const int* __restrict__ idx2,
    const uint4* __restrict__ Bs,
    float* __restrict__ C, float* __restrict__ C2,
    const float* __restrict__ D, const float* __restrict__ bias,
    int M, int N, int K, int lda, int ldc, int KT, int NT)
{
  __shared__ uint4 sA[2][3][256];
  const int tid = threadIdx.x;
  const int lane = tid & 63;
  const int wid = tid >> 6;
  const int m0 = blockIdx.y * 64;
  const int tb = blockIdx.x * 19;
  const bool J5 = (wid < 3);  // wave-uniform: does this wave own a 5th tile?

  const int a_row = m0 + (wid << 4) + (lane & 15);
  const int a_koct = lane >> 4;
  const bool arok = a_row < M;
  const float* Ap = nullptr;
  const float* Ap2 = nullptr;
  const float* Ap3 = nullptr;
  if constexpr (GATHER) {
    int i1 = arok ? idx1[a_row] : 0;
    int i2 = arok ? idx2[a_row] : 0;
    Ap  = A  + (size_t)i1 * lda;
    Ap2 = A2 + (size_t)i2 * lda;
  } else if constexpr (CONCAT) {
    int r = arok ? a_row : 0;
    Ap  = A  + (size_t)r * lda;
    Ap2 = A2 + (size_t)r * lda;
    Ap3 = A3 + (size_t)r * lda;
  } else {
    Ap = A + (size_t)(arok ? a_row : 0) * lda;
  }

  const int PS = KT * NT * 64;  // plane stride (uint4 units)

  f32x4 acc[4][5];
#pragma unroll
  for (int i = 0; i < 4; i++)
#pragma unroll
    for (int j = 0; j < 5; j++) acc[i][j] = (f32x4){0.f, 0.f, 0.f, 0.f};

  float ax[8];
  auto loadA = [&](int kt_) {
    const int gk0 = (kt_ << 5) + (a_koct << 3);
    if constexpr (VEC && !CONCAT) {
      if (arok && gk0 + 8 <= K) {
        float4 p0 = *(const float4*)(Ap + gk0);
        float4 p1 = *(const float4*)(Ap + gk0 + 4);
        if constexpr (GATHER) {
          float4 q0 = *(const float4*)(Ap2 + gk0);
          float4 q1 = *(const float4*)(Ap2 + gk0 + 4);
          ax[0] = p0.x - q0.x; ax[1] = p0.y - q0.y;
          ax[2] = p0.z - q0.z; ax[3] = p0.w - q0.w;
          ax[4] = p1.x - q1.x; ax[5] = p1.y - q1.y;
          ax[6] = p1.z - q1.z; ax[7] = p1.w - q1.w;
        } else {
          ax[0] = p0.x; ax[1] = p0.y; ax[2] = p0.z; ax[3] = p0.w;
          ax[4] = p1.x; ax[5] = p1.y; ax[6] = p1.z; ax[7] = p1.w;
        }
        return;
      }
    }
#pragma unroll
    for (int j = 0; j < 8; j++) {
      int gk = gk0 + j;
      float v = 0.f;
      if (arok && gk < K) {
        if constexpr (GATHER) {
          v = Ap[gk] - Ap2[gk];
        } else if constexpr (CONCAT) {
          int s_ = (gk >= 2 * lda) ? 2 : ((gk >= lda) ? 1 : 0);
          int col = gk - s_ * lda;
          const float* src = (s_ == 0) ? Ap : ((s_ == 1) ? Ap2 : Ap3);
          v = src[col];
        } else {
          v = Ap[gk];
        }
      }
      ax[j] = v;
    }
  };
  auto writeA = [&](int slot) {
    unsigned h[8], m[8], l[8];
#pragma unroll
    for (int j = 0; j < 8; j++) split3(ax[j], h[j], m[j], l[j]);
    uint4 hv, mv, lv;
    pack8(h, hv); pack8(m, mv); pack8(l, lv);
    const int fi = (wid << 6) | lane;
    sA[slot][0][fi] = hv; sA[slot][1][fi] = mv; sA[slot][2][fi] = lv;
  };

  loadA(0);
  writeA(0);
  __syncthreads();

  for (int kt = 0; kt < KT; kt++) {
    const int cur = kt & 1;
    const bool more = kt + 1 < KT;

    const int bk = kt * NT * 64 + tb * 64 + lane;
    bf16x8 breg[5][3];
#pragma unroll
    for (int j = 0; j < 4; j++) {
      const int gidx = bk + (((j << 2) + wid) << 6);
#pragma unroll
      for (int p = 0; p < 3; p++)
        breg[j][p] = ((const bf16x8*)Bs)[gidx + p * PS];
    }
    if (J5) {
      const int gidx = bk + ((16 + wid) << 6);
#pragma unroll
      for (int p = 0; p < 3; p++)
        breg[4][p] = ((const bf16x8*)Bs)[gidx + p * PS];
    }

    if (more) loadA(kt + 1);

    bf16x8 aF[3][4];
#pragma unroll
    for (int p = 0; p < 3; p++)
#pragma unroll
      for (int i = 0; i < 4; i++)
        aF[p][i] = ((const bf16x8*)sA[cur][p])[(i << 6) | lane];

#pragma unroll
    for (int j = 0; j < 5; j++) {
      if (j < 4 || J5) {
#pragma unroll
        for (int i = 0; i < 4; i++) {
          acc[i][j] = __builtin_amdgcn_mfma_f32_16x16x32_bf16(aF[2][i], breg[j][0], acc[i][j], 0, 0, 0);
          acc[i][j] = __builtin_amdgcn_mfma_f32_16x16x32_bf16(aF[0][i], breg[j][2], acc[i][j], 0, 0, 0);
          acc[i][j] = __builtin_amdgcn_mfma_f32_16x16x32_bf16(aF[1][i], breg[j][1], acc[i][j], 0, 0, 0);
          acc[i][j] = __builtin_amdgcn_mfma_f32_16x16x32_bf16(aF[1][i], breg[j][0], acc[i][j], 0, 0, 0);
          acc[i][j] = __builtin_amdgcn_mfma_f32_16x16x32_bf16(aF[0][i], breg[j][1], acc[i][j], 0, 0, 0);
          acc[i][j] = __builtin_amdgcn_mfma_f32_16x16x32_bf16(aF[0][i], breg[j][0], acc[i][j], 0, 0, 0);
        }
      }
    }
    if (more) writeA(cur ^ 1);
    __syncthreads();
  }

  // epilogue: C/D layout col=lane&15, row=(lane>>4)*4+r ; tile t = 4j + wid
  const int cr = (lane >> 4) << 2;
  const int cc = lane & 15;
#pragma unroll
  for (int j = 0; j < 5; j++) {
    if (j == 4 && !J5) break;
    const int t = (j << 2) + wid;
    const int gn = ((tb + t) << 4) + cc;
    if (gn >= N) continue;
#pragma unroll
    for (int i = 0; i < 4; i++) {
#pragma unroll
      for (int r = 0; r < 4; r++) {
        const int gm = m0 + (i << 4) + cr + r;
        if (gm >= M) continue;
        const size_t rowoff = (size_t)gm * ldc;
        float v = acc[i][j][r];
        if constexpr (ADDMAT) v += D[rowoff + gn];
        if constexpr (BIAS) v += bias[gn];
        if constexpr (RELU) v = fmaxf(v, 0.f);
        C[rowoff + gn] = v;
        if constexpr (W2) C2[rowoff + gn] = v;
      }
    }
  }
}

// ============== neighbor aggregation (float4): sum * max over 6 ==============
template<bool UPDATE>
__global__ __launch_bounds__(256) void agg_kernel(
    const float* __restrict__ message_bond, const int* __restrict__ a2b,
    float* __restrict__ out)
{
  int gid = blockIdx.x * 256 + threadIdx.x;
  if (gid >= NAt * 75) return;
  int a = gid / 75;
  int c4 = gid - a * 75;
  const int* ab = a2b + (size_t)a * 6;
  float4 s = {0.f, 0.f, 0.f, 0.f};
  float4 mx = {-3.0e38f, -3.0e38f, -3.0e38f, -3.0e38f};
#pragma unroll
  for (int j = 0; j < 6; j++) {
    float4 v = *(const float4*)(message_bond + (size_t)ab[j] * H + c4 * 4);
    s.x += v.x; s.y += v.y; s.z += v.z; s.w += v.w;
    mx.x = fmaxf(mx.x, v.x); mx.y = fmaxf(mx.y, v.y);
    mx.z = fmaxf(mx.z, v.z); mx.w = fmaxf(mx.w, v.w);
  }
  float4* o = (float4*)(out + (size_t)a * H + c4 * 4);
  float4 r;
  r.x = s.x * mx.x; r.y = s.y * mx.y; r.z = s.z * mx.z; r.w = s.w * mx.w;
  if (UPDATE) {
    float4 c = *o;
    r.x += c.x; r.y += c.y; r.z += c.z; r.w += c.w;
  }
  *o = r;
}

// ======================= misc elementwise =======================
__global__ __launch_bounds__(256) void msg_kernel(
    const float* __restrict__ node, const float* __restrict__ gru_bias,
    float* __restrict__ msg)
{
  int gid = blockIdx.x * 256 + threadIdx.x;
  if (gid >= NAt * H) return;
  int hh = gid % H;
  msg[gid] = fmaxf(node[gid] + gru_bias[hh], 0.f);
}

// h0 + zero the GRU group-barrier cells (runs before gru_persist in-stream)
__global__ __launch_bounds__(256) void h0_kernel(
    const float* __restrict__ node, float* __restrict__ h0,
    int* __restrict__ bar)
{
  int gid = blockIdx.x * 256 + threadIdx.x;
  if (gid < 1024) bar[gid] = 0;
  if (gid >= NM * H) return;
  int m = gid / H;
  int hh = gid - m * H;
  const float* base = node + ((size_t)(1 + m * APM)) * H + hh;
  float mx = base[0];
  for (int t = 1; t < APM; t++) mx = fmaxf(mx, base[(size_t)t * H]);
  h0[gid] = mx;
}

__global__ __launch_bounds__(256) void row0_kernel(
    const float* __restrict__ msg, float* __restrict__ message)
{
  int gid = blockIdx.x * 256 + threadIdx.x;
  if (gid >= 2 * H) return;
  message[gid] = msg[gid % H];
}

__global__ __launch_bounds__(256) void mean_kernel(
    const float* __restrict__ ah, float* __restrict__ out)
{
  int gid = blockIdx.x * 256 + threadIdx.x;
  if (gid >= NM * H) return;
  int m = gid / H;
  int hh = gid - m * H;
  const float* base = ah + ((size_t)(1 + m * APM)) * H + hh;
  float s = 0.f;
#pragma unroll 8
  for (int t = 0; t < APM; t++) s += base[(size_t)t * H];
  out[gid] = s * (1.f / APM);
}

// ======================= GRU: persistent, all 65 steps in ONE launch =======================
// r16: replaces 65 serial launches. Same per-step structure as the proven
// gru_step_kernel (256 blocks: ct=gate-chunk, mg=mol-group, dir), with:
//  - h state in an LDS ping-pong pair (each block recomputes h locally,
//    as before) -> hbuf global round-trip eliminated.
//  - gates (gbuf) still global ping-pong; the only cross-block dep is the
//    4 ct-blocks of one (dir,mg) group -> GROUP-LOCAL barrier (atomic
//    monotonic counter per group, device-scope, threadfence release/acquire).
//    256 blocks x 256 thr x 19.2KB LDS on 256 CUs: trivially co-resident.
__global__ __launch_bounds__(256) void gru_persist_kernel(
    const float* __restrict__ xg_f, const float* __restrict__ xg_b,
    const float* __restrict__ w_hh_f, const float* __restrict__ w_hh_b,
    const float* __restrict__ b_hh_f, const float* __restrict__ b_hh_b,
    const float* __restrict__ h0,
    float* __restrict__ g_buf,   // [2][2][NM][H3]
    float* __restrict__ message, // [NAt][600]
    int* __restrict__ bar)       // [64 groups * 16] zeroed by h0_kernel
{
  __shared__ float h_lds[2][8 * H];
  const int tid = threadIdx.x;
  const int b = blockIdx.x;
  const int ct = b & 3;
  const int mg = (b >> 2) & 31;
  const int dir = b >> 7;
  const int grp = b >> 2;            // 0..63 (dir*32 + mg)
  int* gbar = bar + grp * 16;
  const float* xg = dir ? xg_b : xg_f;
  const float* whh = dir ? w_hh_b : w_hh_f;
  const float* bhh = dir ? b_hh_b : b_hh_f;

  for (int s = 0; s <= 64; s++) {
    const int r = s & 1;
    const int w = 1 - r;
    float* hl_w = h_lds[s & 1];
    const float* hl_r = h_lds[(s + 1) & 1];
    const float* gb_r = g_buf + ((size_t)(r * 2 + dir)) * NM * H3;
    float* gb_w = g_buf + ((size_t)(w * 2 + dir)) * NM * H3;
    int t_prev = 0;
    if (s > 0) t_prev = dir ? (64 - s) : (s - 1);

    // phase 1: h(s) for this block's 8 mols (local recompute, as before)
    for (int i = tid; i < 8 * H; i += 256) {
      int m = i / H;
      int hh = i - m * H;
      int mol = mg * 8 + m;
      float hc;
      if (s == 0) {
        hc = h0[(size_t)mol * H + hh];
      } else {
        const float* xr = xg + ((size_t)(mol * 64 + t_prev)) * H3;
        float ir = xr[hh], iz = xr[H + hh], inn = xr[2 * H + hh];
        const float* gp = gb_r + (size_t)mol * H3;
        float hr = gp[hh], hz = gp[H + hh], hn = gp[2 * H + hh];
        float hp = hl_r[i];
        float rr = 1.f / (1.f + expf(-(ir + hr)));
        float zz = 1.f / (1.f + expf(-(iz + hz)));
        float nn = tanhf(inn + rr * hn);
        hc = (1.f - zz) * nn + zz * hp;
      }
      hl_w[i] = hc;
      if (ct == 0 && s > 0) {
        int row = 1 + mol * 64 + t_prev;
        message[(size_t)row * 600 + dir * H + hh] = hc;
      }
    }
    __syncthreads();
    if (s == 64) break;   // final h written to message; no more gates needed

    // phase 2: thread t (<225) owns gate g = ct*225+t, all 8 mol dots from LDS
    if (tid < 225) {
      const int g = ct * 225 + tid;
      const float4* wr = (const float4*)(whh + (size_t)g * H);
      float acc[8];
#pragma unroll
      for (int m = 0; m < 8; m++) acc[m] = 0.f;
      for (int k0 = 0; k0 < 75; k0 += 3) {
        float4 w0 = wr[k0];
        float4 w1 = wr[k0 + 1];
        float4 w2 = wr[k0 + 2];
#pragma unroll
        for (int m = 0; m < 8; m++) {
          const float4* hm = (const float4*)(hl_w + m * H);
          float4 a0 = hm[k0];
          float4 a1 = hm[k0 + 1];
          float4 a2 = hm[k0 + 2];
          acc[m] += w0.x * a0.x + w0.y * a0.y + w0.z * a0.z + w0.w * a0.w
                  + w1.x * a1.x + w1.y * a1.y + w1.z * a1.z + w1.w * a1.w
                  + w2.x * a2.x + w2.y * a2.y + w2.z * a2.z + w2.w * a2.w;
        }
      }
      const float bb = bhh[g];
#pragma unroll
      for (int m = 0; m < 8; m++)
        gb_w[(size_t)(mg * 8 + m) * H3 + g] = acc[m] + bb;
    }
    __syncthreads();

    // group barrier: all 4 ct-blocks' gate writes visible before next phase 1
    if (tid == 0) {
      __threadfence();                       // release gb_w writes (device scope)
      atomicAdd(gbar, 1);
      int target = 4 * (s + 1);              // monotonic counter: no reset race
      while (atomicAdd(gbar, 0) < target) {
        __builtin_amdgcn_s_sleep(1);
      }
      __threadfence();                       // acquire other blocks' writes
    }
    __syncthreads();
  }
}

// ======================= host =======================
// Base layout 63,898,800 floats = 255.6 MB + pre-split weights 9.2 MB at tail.
extern "C" void kernel_launch(void* const* d_in, const int* in_sizes, int n_in,
                              void* d_out, int out_size, void* d_ws, size_t ws_size,
                              hipStream_t stream) {
  (void)in_sizes; (void)n_in; (void)out_size; (void)ws_size;
  const float* f_atoms  = (const float*)d_in[0];
  const float* f_bonds  = (const float*)d_in[1];
  const int*   a2b      = (const int*)d_in[2];
  const int*   b2a      = (const int*)d_in[3];
  const int*   b2revb   = (const int*)d_in[4];
  const float* W_i_atom = (const float*)d_in[5];
  const float* W_i_bond = (const float*)d_in[6];
  const float* W_h      = (const float*)d_in[7];
  const float* W_lr     = (const float*)d_in[8];
  const float* W_o      = (const float*)d_in[9];
  const float* b_o      = (const float*)d_in[10];
  const float* gru_bias = (const float*)d_in[11];
  const float* w_ih_f   = (const float*)d_in[12];
  const float* w_hh_f   = (const float*)d_in[13];
  const float* b_ih_f   = (const float*)d_in[14];
  const float* b_hh_f   = (const float*)d_in[15];
  const float* w_ih_b   = (const float*)d_in[16];
  const float* w_hh_b   = (const float*)d_in[17];
  const float* b_ih_b   = (const float*)d_in[18];
  const float* b_hh_b   = (const float*)d_in[19];

  float* ws = (float*)d_ws;
  const size_t SZ_B = (size_t)NBd * H;  // 19,661,100
  const size_t SZ_A = (size_t)NAt * H;  //  4,915,500

  float* ib  = ws;
  float* mb0 = ws + SZ_B;
  float* mb1 = ws + 2 * SZ_B;
  float* ma  = ws + 3 * SZ_B;
  float* xgf     = ib;
  float* message = mb0;
  float* h0      = mb0 + 9831000;
  float* hbuf    = h0 + (size_t)NM * H + 2 * (size_t)H * H3;  // now: barrier cells
  float* gbuf    = hbuf + (size_t)4 * NM * H;
  float* aggb    = mb1;
  float* node    = mb1 + SZ_A;
  float* iat     = mb1 + 2 * SZ_A;
  float* msg     = mb1 + 14745600;
  float* xgb     = mb1;
  float* ah      = ma;
  int*   bar     = (int*)hbuf;

  // pre-split weight region at tail (uint4 granule counts)
  const size_t BASE_FLOATS = 63898800;
  uint4* wsp = (uint4*)(ws + BASE_FLOATS);
  const int G_IA = 5 * 19 * 64;
  const int G_IB = 5 * 19 * 64;
  const int G_WH = 10 * 19 * 64;
  const int G_LR = 29 * 19 * 64;
  const int G_WT = 10 * 57 * 64;
  const int G_WO = 19 * 19 * 64;
  uint4* sp_ia = wsp;
  uint4* sp_ib = sp_ia + 3 * G_IA;
  uint4* sp_wh = sp_ib + 3 * G_IB;
  uint4* sp_lr = sp_wh + 4 * 3 * G_WH;
  uint4* sp_tf = sp_lr + 3 * G_LR;
  uint4* sp_tb = sp_tf + 3 * G_WT;
  uint4* sp_wo = sp_tb + 3 * G_WT;

  dim3 blk(256);
  // all N used here are exact multiples of 19 tiles (300->19, 912->57)
  auto gg3 = [](int M, int NT) {
    return dim3((unsigned)(NT / 19), (unsigned)((M + 63) / 64));
  };
  auto pg = [](int gran) { return dim3((unsigned)((gran + 255) / 256)); };
  const int gA4 = (int)((NAt * 75 + 255) / 256);
  const int gAe = (int)((SZ_A + 255) / 256);

  // ---- weight prep ----
  prep_split_kernel<false><<<pg(G_IA), blk, 0, stream>>>(W_i_atom, sp_ia, 133, 300, 300, 5, 19);
  prep_split_kernel<false><<<pg(G_IB), blk, 0, stream>>>(W_i_bond, sp_ib, 147, 300, 300, 5, 19);
  for (int d = 0; d < 4; d++)
    prep_split_kernel<false><<<pg(G_WH), blk, 0, stream>>>(
        W_h + (size_t)d * H * H, sp_wh + (size_t)d * 3 * G_WH, 300, 300, 300, 10, 19);
  prep_split_kernel<false><<<pg(G_LR), blk, 0, stream>>>(W_lr, sp_lr, 900, 300, 300, 29, 19);
  prep_split_kernel<true><<<pg(G_WT), blk, 0, stream>>>(w_ih_f, sp_tf, 300, 900, 300, 10, 57);
  prep_split_kernel<true><<<pg(G_WT), blk, 0, stream>>>(w_ih_b, sp_tb, 300, 900, 300, 10, 57);
  prep_split_kernel<false><<<pg(G_WO), blk, 0, stream>>>(W_o, sp_wo, 600, 300, 300, 19, 19);

  // ma = relu(f_atoms @ W_i_atom)
  gemm_mfma3<false,false,true,false,false,false,false><<<gg3(NAt, 19), blk, 0, stream>>>(
      f_atoms, nullptr, nullptr, nullptr, nullptr, sp_ia, ma, nullptr, nullptr, nullptr,
      NAt, H, 133, 133, H, 5, 19);
  // ib = relu(f_bonds @ W_i_bond); mb0 = copy
  gemm_mfma3<false,false,true,false,false,true,false><<<gg3(NBd, 19), blk, 0, stream>>>(
      f_bonds, nullptr, nullptr, nullptr, nullptr, sp_ib, ib, mb0, nullptr, nullptr,
      NBd, H, 147, 147, H, 5, 19);

  float* mbp[2] = {mb0, mb1};
  int cur = 0;
  for (int d = 0; d < 4; d++) {
    agg_kernel<true><<<gA4, blk, 0, stream>>>(mbp[cur], a2b, ma);
    gemm_mfma3<true,false,true,true,false,false,true><<<gg3(NBd, 19), blk, 0, stream>>>(
        ma, mbp[cur], nullptr, b2a, b2revb, sp_wh + (size_t)d * 3 * G_WH,
        mbp[1 - cur], nullptr, ib, nullptr, NBd, H, H, H, H, 10, 19);
    cur ^= 1;
  }
  agg_kernel<false><<<gA4, blk, 0, stream>>>(mb0, a2b, aggb);

  gemm_mfma3<false,false,true,false,false,false,false><<<gg3(NAt, 19), blk, 0, stream>>>(
      f_atoms, nullptr, nullptr, nullptr, nullptr, sp_ia, iat, nullptr, nullptr, nullptr,
      NAt, H, 133, 133, H, 5, 19);
  gemm_mfma3<false,false,false,false,true,false,false><<<gg3(NAt, 19), blk, 0, stream>>>(
      aggb, ma, iat, nullptr, nullptr, sp_lr, node, nullptr, nullptr, nullptr,
      NAt, H, 900, H, H, 29, 19);

  h0_kernel<<<(NM * H + 255) / 256, blk, 0, stream>>>(node, h0, bar);
  msg_kernel<<<gAe, blk, 0, stream>>>(node, gru_bias, msg);

  gemm_mfma3<false,true,false,false,false,false,true><<<gg3(16384, 57), blk, 0, stream>>>(
      msg + H, nullptr, nullptr, nullptr, nullptr, sp_tf, xgf, nullptr, nullptr, b_ih_f,
      16384, H3, H, H, H3, 10, 57);
  gemm_mfma3<false,true,false,false,false,false,true><<<gg3(16384, 57), blk, 0, stream>>>(
      msg + H, nullptr, nullptr, nullptr, nullptr, sp_tb, xgb, nullptr, nullptr, b_ih_b,
      16384, H3, H, H, H3, 10, 57);

  // all 65 GRU steps in one persistent (regular) launch
  gru_persist_kernel<<<256, blk, 0, stream>>>(
      xgf, xgb, w_hh_f, w_hh_b, b_hh_f, b_hh_b, h0, gbuf, message, bar);

  row0_kernel<<<3, blk, 0, stream>>>(msg, message);

  gemm_mfma3<false,true,true,false,false,false,true><<<gg3(NAt, 19), blk, 0, stream>>>(
      message, nullptr, nullptr, nullptr, nullptr, sp_wo, ah, nullptr, nullptr, b_o,
      NAt, H, 600, 600, H, 19, 19);
  mean_kernel<<<(NM * H + 255) / 256, blk, 0, stream>>>(ah, (float*)d_out);
}

// Round 8
// 3591.983 us; speedup vs baseline: 1.0043x; 1.0043x over previous
//
#include <hip/hip_runtime.h>
#include <math.h>

#define H 300
#define H3 900
#define NAt 16385
#define NBd 65537
#define NM 256
#define APM 64

typedef __attribute__((ext_vector_type(8))) short bf16x8;
typedef __attribute__((ext_vector_type(4))) float f32x4;

__device__ __forceinline__ unsigned bf16_rne(float x) {
  unsigned u = __float_as_uint(x);
  return (u + 0x7fffu + ((u >> 16) & 1u)) >> 16;
}
__device__ __forceinline__ float bf16_up(unsigned h) {
  return __uint_as_float(h << 16);
}
// 3-way split: x ~= h + m + l (each bf16), residual ~2^-26 |x|
__device__ __forceinline__ void split3(float x, unsigned &h, unsigned &m, unsigned &l) {
  h = bf16_rne(x);
  float r1 = x - bf16_up(h);
  m = bf16_rne(r1);
  float r2 = r1 - bf16_up(m);
  l = bf16_rne(r2);
}
__device__ __forceinline__ void pack8(const unsigned* v, uint4 &o) {
  o.x = v[0] | (v[1] << 16); o.y = v[2] | (v[3] << 16);
  o.z = v[4] | (v[5] << 16); o.w = v[6] | (v[7] << 16);
}

// ======================= weight pre-split =======================
template<bool TRANS>
__global__ __launch_bounds__(256) void prep_split_kernel(
    const float* __restrict__ B, uint4* __restrict__ out,
    int K, int N, int ldb, int KT, int NT)
{
  int g = blockIdx.x * 256 + threadIdx.x;
  int total = KT * NT * 64;
  if (g >= total) return;
  int lane = g & 63;
  int t = (g >> 6) % NT;
  int kt = (g >> 6) / NT;
  int n = t * 16 + (lane & 15);
  int kb = kt * 32 + ((lane >> 4) << 3);
  float x[8];
#pragma unroll
  for (int j = 0; j < 8; j++) {
    int gk = kb + j;
    float v = 0.f;
    if (n < N && gk < K)
      v = TRANS ? B[(size_t)n * ldb + gk] : B[(size_t)gk * ldb + n];
    x[j] = v;
  }
  unsigned h[8], m[8], l[8];
#pragma unroll
  for (int j = 0; j < 8; j++) split3(x[j], h[j], m[j], l[j]);
  uint4 hv, mv, lv;
  pack8(h, hv); pack8(m, mv); pack8(l, lv);
  out[g] = hv;
  out[total + g] = mv;
  out[2 * total + g] = lv;
}

// ============== split-bf16 MFMA GEMM (EXACT r12 — proven) ==============
template<bool ADDMAT, bool BIAS, bool RELU, bool GATHER, bool CONCAT, bool W2, bool VEC>
__global__ __launch_bounds__(256, 2) void gemm_mfma3(
    const float* __restrict__ A, const float* __restrict__ A2,
    const float* __restrict__ A3,
    const int* __restrict__ idx1, const int* __restrict__ idx2,
    const uint4* __restrict__ Bs,
    float* __restrict__ C, float* __restrict__ C2,
    const float* __restrict__ D, const float* __restrict__ bias,
    int M, int N, int K, int lda, int ldc, int KT, int NT)
{
  __shared__ uint4 sA[2][3][256];
  const int tid = threadIdx.x;
  const int lane = tid & 63;
  const int wid = tid >> 6;
  const int m0 = blockIdx.y * 64;
  const int tb = blockIdx.x * 19;
  const bool J5 = (wid < 3);  // wave-uniform: does this wave own a 5th tile?

  const int a_row = m0 + (wid << 4) + (lane & 15);
  const int a_koct = lane >> 4;
  const bool arok = a_row < M;
  const float* Ap = nullptr;
  const float* Ap2 = nullptr;
  const float* Ap3 = nullptr;
  if constexpr (GATHER) {
    int i1 = arok ? idx1[a_row] : 0;
    int i2 = arok ? idx2[a_row] : 0;
    Ap  = A  + (size_t)i1 * lda;
    Ap2 = A2 + (size_t)i2 * lda;
  } else if constexpr (CONCAT) {
    int r = arok ? a_row : 0;
    Ap  = A  + (size_t)r * lda;
    Ap2 = A2 + (size_t)r * lda;
    Ap3 = A3 + (size_t)r * lda;
  } else {
    Ap = A + (size_t)(arok ? a_row : 0) * lda;
  }

  const int PS = KT * NT * 64;  // plane stride (uint4 units)

  f32x4 acc[4][5];
#pragma unroll
  for (int i = 0; i < 4; i++)
#pragma unroll
    for (int j = 0; j < 5; j++) acc[i][j] = (f32x4){0.f, 0.f, 0.f, 0.f};

  float ax[8];
  auto loadA = [&](int kt_) {
    const int gk0 = (kt_ << 5) + (a_koct << 3);
    if constexpr (VEC && !CONCAT) {
      if (arok && gk0 + 8 <= K) {
        float4 p0 = *(const float4*)(Ap + gk0);
        float4 p1 = *(const float4*)(Ap + gk0 + 4);
        if constexpr (GATHER) {
          float4 q0 = *(const float4*)(Ap2 + gk0);
          float4 q1 = *(const float4*)(Ap2 + gk0 + 4);
          ax[0] = p0.x - q0.x; ax[1] = p0.y - q0.y;
          ax[2] = p0.z - q0.z; ax[3] = p0.w - q0.w;
          ax[4] = p1.x - q1.x; ax[5] = p1.y - q1.y;
          ax[6] = p1.z - q1.z; ax[7] = p1.w - q1.w;
        } else {
          ax[0] = p0.x; ax[1] = p0.y; ax[2] = p0.z; ax[3] = p0.w;
          ax[4] = p1.x; ax[5] = p1.y; ax[6] = p1.z; ax[7] = p1.w;
        }
        return;
      }
    }
#pragma unroll
    for (int j = 0; j < 8; j++) {
      int gk = gk0 + j;
      float v = 0.f;
      if (arok && gk < K) {
        if constexpr (GATHER) {
          v = Ap[gk] - Ap2[gk];
        } else if constexpr (CONCAT) {
          int s_ = (gk >= 2 * lda) ? 2 : ((gk >= lda) ? 1 : 0);
          int col = gk - s_ * lda;
          const float* src = (s_ == 0) ? Ap : ((s_ == 1) ? Ap2 : Ap3);
          v = src[col];
        } else {
          v = Ap[gk];
        }
      }
      ax[j] = v;
    }
  };
  auto writeA = [&](int slot) {
    unsigned h[8], m[8], l[8];
#pragma unroll
    for (int j = 0; j < 8; j++) split3(ax[j], h[j], m[j], l[j]);
    uint4 hv, mv, lv;
    pack8(h, hv); pack8(m, mv); pack8(l, lv);
    const int fi = (wid << 6) | lane;
    sA[slot][0][fi] = hv; sA[slot][1][fi] = mv; sA[slot][2][fi] = lv;
  };

  loadA(0);
  writeA(0);
  __syncthreads();

  for (int kt = 0; kt < KT; kt++) {
    const int cur = kt & 1;
    const bool more = kt + 1 < KT;

    const int bk = kt * NT * 64 + tb * 64 + lane;
    bf16x8 breg[5][3];
#pragma unroll
    for (int j = 0; j < 4; j++) {
      const int gidx = bk + (((j << 2) + wid) << 6);
#pragma unroll
      for (int p = 0; p < 3; p++)
        breg[j][p] = ((const bf16x8*)Bs)[gidx + p * PS];
    }
    if (J5) {
      const int gidx = bk + ((16 + wid) << 6);
#pragma unroll
      for (int p = 0; p < 3; p++)
        breg[4][p] = ((const bf16x8*)Bs)[gidx + p * PS];
    }

    if (more) loadA(kt + 1);

    bf16x8 aF[3][4];
#pragma unroll
    for (int p = 0; p < 3; p++)
#pragma unroll
      for (int i = 0; i < 4; i++)
        aF[p][i] = ((const bf16x8*)sA[cur][p])[(i << 6) | lane];

#pragma unroll
    for (int j = 0; j < 5; j++) {
      if (j < 4 || J5) {
#pragma unroll
        for (int i = 0; i < 4; i++) {
          acc[i][j] = __builtin_amdgcn_mfma_f32_16x16x32_bf16(aF[2][i], breg[j][0], acc[i][j], 0, 0, 0);
          acc[i][j] = __builtin_amdgcn_mfma_f32_16x16x32_bf16(aF[0][i], breg[j][2], acc[i][j], 0, 0, 0);
          acc[i][j] = __builtin_amdgcn_mfma_f32_16x16x32_bf16(aF[1][i], breg[j][1], acc[i][j], 0, 0, 0);
          acc[i][j] = __builtin_amdgcn_mfma_f32_16x16x32_bf16(aF[1][i], breg[j][0], acc[i][j], 0, 0, 0);
          acc[i][j] = __builtin_amdgcn_mfma_f32_16x16x32_bf16(aF[0][i], breg[j][1], acc[i][j], 0, 0, 0);
          acc[i][j] = __builtin_amdgcn_mfma_f32_16x16x32_bf16(aF[0][i], breg[j][0], acc[i][j], 0, 0, 0);
        }
      }
    }
    if (more) writeA(cur ^ 1);
    __syncthreads();
  }

  // epilogue: C/D layout col=lane&15, row=(lane>>4)*4+r ; tile t = 4j + wid
  const int cr = (lane >> 4) << 2;
  const int cc = lane & 15;
#pragma unroll
  for (int j = 0; j < 5; j++) {
    if (j == 4 && !J5) break;
    const int t = (j << 2) + wid;
    const int gn = ((tb + t) << 4) + cc;
    if (gn >= N) continue;
#pragma unroll
    for (int i = 0; i < 4; i++) {
#pragma unroll
      for (int r = 0; r < 4; r++) {
        const int gm = m0 + (i << 4) + cr + r;
        if (gm >= M) continue;
        const size_t rowoff = (size_t)gm * ldc;
        float v = acc[i][j][r];
        if constexpr (ADDMAT) v += D[rowoff + gn];
        if constexpr (BIAS) v += bias[gn];
        if constexpr (RELU) v = fmaxf(v, 0.f);
        C[rowoff + gn] = v;
        if constexpr (W2) C2[rowoff + gn] = v;
      }
    }
  }
}

// ============== neighbor aggregation (float4): sum * max over 6 ==============
template<bool UPDATE>
__global__ __launch_bounds__(256) void agg_kernel(
    const float* __restrict__ message_bond, const int* __restrict__ a2b,
    float* __restrict__ out)
{
  int gid = blockIdx.x * 256 + threadIdx.x;
  if (gid >= NAt * 75) return;
  int a = gid / 75;
  int c4 = gid - a * 75;
  const int* ab = a2b + (size_t)a * 6;
  float4 s = {0.f, 0.f, 0.f, 0.f};
  float4 mx = {-3.0e38f, -3.0e38f, -3.0e38f, -3.0e38f};
#pragma unroll
  for (int j = 0; j < 6; j++) {
    float4 v = *(const float4*)(message_bond + (size_t)ab[j] * H + c4 * 4);
    s.x += v.x; s.y += v.y; s.z += v.z; s.w += v.w;
    mx.x = fmaxf(mx.x, v.x); mx.y = fmaxf(mx.y, v.y);
    mx.z = fmaxf(mx.z, v.z); mx.w = fmaxf(mx.w, v.w);
  }
  float4* o = (float4*)(out + (size_t)a * H + c4 * 4);
  float4 r;
  r.x = s.x * mx.x; r.y = s.y * mx.y; r.z = s.z * mx.z; r.w = s.w * mx.w;
  if (UPDATE) {
    float4 c = *o;
    r.x += c.x; r.y += c.y; r.z += c.z; r.w += c.w;
  }
  *o = r;
}

// ======================= misc elementwise =======================
__global__ __launch_bounds__(256) void msg_kernel(
    const float* __restrict__ node, const float* __restrict__ gru_bias,
    float* __restrict__ msg)
{
  int gid = blockIdx.x * 256 + threadIdx.x;
  if (gid >= NAt * H) return;
  int hh = gid % H;
  msg[gid] = fmaxf(node[gid] + gru_bias[hh], 0.f);
}

__global__ __launch_bounds__(256) void h0_kernel(
    const float* __restrict__ node, float* __restrict__ h0)
{
  int gid = blockIdx.x * 256 + threadIdx.x;
  if (gid >= NM * H) return;
  int m = gid / H;
  int hh = gid - m * H;
  const float* base = node + ((size_t)(1 + m * APM)) * H + hh;
  float mx = base[0];
  for (int t = 1; t < APM; t++) mx = fmaxf(mx, base[(size_t)t * H]);
  h0[gid] = mx;
}

__global__ __launch_bounds__(256) void row0_kernel(
    const float* __restrict__ msg, float* __restrict__ message)
{
  int gid = blockIdx.x * 256 + threadIdx.x;
  if (gid >= 2 * H) return;
  message[gid] = msg[gid % H];
}

__global__ __launch_bounds__(256) void mean_kernel(
    const float* __restrict__ ah, float* __restrict__ out)
{
  int gid = blockIdx.x * 256 + threadIdx.x;
  if (gid >= NM * H) return;
  int m = gid / H;
  int hh = gid - m * H;
  const float* base = ah + ((size_t)(1 + m * APM)) * H + hh;
  float s = 0.f;
#pragma unroll 8
  for (int t = 0; t < APM; t++) s += base[(size_t)t * H];
  out[gid] = s * (1.f / APM);
}

// ======================= GRU: block-independent, all 65 steps, ONE launch =======================
// r17: the cross-block dependency (gates split over 4 ct-blocks) is what
// forced either 65 launches (22us/step: launch + L2 re-warm each step) or
// device-scope fences (r16: 35us/step, L2 invalidated every step -> FETCH
// 437MB). Eliminated: each block owns 4 mols x ONE dir and computes ALL 900
// gates for them -> only __syncthreads, no fences, W stays L2-resident.
// 128 blocks (2 dir x 64 mol-groups) x 256 thr; h ping-pong + gates in LDS.
// Per-element FP sequences identical to the r9/r12 kernels -> same output.
__global__ __launch_bounds__(256) void gru_fused_kernel(
    const float* __restrict__ xg_f, const float* __restrict__ xg_b,
    const float* __restrict__ w_hh_f, const float* __restrict__ w_hh_b,
    const float* __restrict__ b_hh_f, const float* __restrict__ b_hh_b,
    const float* __restrict__ h0,
    float* __restrict__ message) // [NAt][600]
{
  __shared__ __attribute__((aligned(16))) float h_lds[2][4 * H];
  __shared__ __attribute__((aligned(16))) float g_lds[4 * H3];
  const int tid = threadIdx.x;
  const int b = blockIdx.x;
  const int mg = b & 63;
  const int dir = b >> 6;
  const int mol0 = mg * 4;
  const float* xg = dir ? xg_b : xg_f;
  const float* whh = dir ? w_hh_b : w_hh_f;
  const float* bhh = dir ? b_hh_b : b_hh_f;

  for (int s = 0; s <= 64; s++) {
    float* hl_w = h_lds[s & 1];
    const float* hl_r = h_lds[(s ^ 1) & 1];
    int t_prev = 0;
    if (s > 0) t_prev = dir ? (64 - s) : (s - 1);

    // phase 1: h(s) for this block's 4 mols; write message row for t_prev
    for (int i = tid; i < 4 * H; i += 256) {
      int m = i / H;
      int hh = i - m * H;
      int mol = mol0 + m;
      float hc;
      if (s == 0) {
        hc = h0[(size_t)mol * H + hh];
      } else {
        const float* xr = xg + ((size_t)(mol * 64 + t_prev)) * H3;
        float ir = xr[hh], iz = xr[H + hh], inn = xr[2 * H + hh];
        const float* gp = g_lds + m * H3;
        float hr = gp[hh], hz = gp[H + hh], hn = gp[2 * H + hh];
        float hp = hl_r[i];
        float rr = 1.f / (1.f + expf(-(ir + hr)));
        float zz = 1.f / (1.f + expf(-(iz + hz)));
        float nn = tanhf(inn + rr * hn);
        hc = (1.f - zz) * nn + zz * hp;
      }
      hl_w[i] = hc;
      if (s > 0) {
        int row = 1 + mol * 64 + t_prev;
        message[(size_t)row * 600 + dir * H + hh] = hc;
      }
    }
    __syncthreads();
    if (s == 64) break;

    // phase 2: thread t (<225) owns 4 gates g = jg*225+t, 4 mol-accs each.
    // W row per gate read once (float4, L2-resident); h via LDS broadcast.
    if (tid < 225) {
      float acc[4][4];
#pragma unroll
      for (int jg = 0; jg < 4; jg++)
#pragma unroll
        for (int m = 0; m < 4; m++) acc[jg][m] = 0.f;
      const float4* wr[4];
#pragma unroll
      for (int jg = 0; jg < 4; jg++)
        wr[jg] = (const float4*)(whh + (size_t)(jg * 225 + tid) * H);
      for (int k0 = 0; k0 < 75; k0 += 3) {
#pragma unroll
        for (int jg = 0; jg < 4; jg++) {
          float4 w0 = wr[jg][k0];
          float4 w1 = wr[jg][k0 + 1];
          float4 w2 = wr[jg][k0 + 2];
#pragma unroll
          for (int m = 0; m < 4; m++) {
            const float4* hm = (const float4*)(hl_w + m * H);
            float4 a0 = hm[k0];
            float4 a1 = hm[k0 + 1];
            float4 a2 = hm[k0 + 2];
            acc[jg][m] += w0.x * a0.x + w0.y * a0.y + w0.z * a0.z + w0.w * a0.w
                        + w1.x * a1.x + w1.y * a1.y + w1.z * a1.z + w1.w * a1.w
                        + w2.x * a2.x + w2.y * a2.y + w2.z * a2.z + w2.w * a2.w;
          }
        }
      }
#pragma unroll
      for (int jg = 0; jg < 4; jg++) {
        const int g = jg * 225 + tid;
        const float bb = bhh[g];
#pragma unroll
        for (int m = 0; m < 4; m++)
          g_lds[m * H3 + g] = acc[jg][m] + bb;
      }
    }
    __syncthreads();
  }
}

// ======================= host =======================
// Base layout 63,898,800 floats = 255.6 MB + pre-split weights 9.2 MB at tail.
extern "C" void kernel_launch(void* const* d_in, const int* in_sizes, int n_in,
                              void* d_out, int out_size, void* d_ws, size_t ws_size,
                              hipStream_t stream) {
  (void)in_sizes; (void)n_in; (void)out_size; (void)ws_size;
  const float* f_atoms  = (const float*)d_in[0];
  const float* f_bonds  = (const float*)d_in[1];
  const int*   a2b      = (const int*)d_in[2];
  const int*   b2a      = (const int*)d_in[3];
  const int*   b2revb   = (const int*)d_in[4];
  const float* W_i_atom = (const float*)d_in[5];
  const float* W_i_bond = (const float*)d_in[6];
  const float* W_h      = (const float*)d_in[7];
  const float* W_lr     = (const float*)d_in[8];
  const float* W_o      = (const float*)d_in[9];
  const float* b_o      = (const float*)d_in[10];
  const float* gru_bias = (const float*)d_in[11];
  const float* w_ih_f   = (const float*)d_in[12];
  const float* w_hh_f   = (const float*)d_in[13];
  const float* b_ih_f   = (const float*)d_in[14];
  const float* b_hh_f   = (const float*)d_in[15];
  const float* w_ih_b   = (const float*)d_in[16];
  const float* w_hh_b   = (const float*)d_in[17];
  const float* b_ih_b   = (const float*)d_in[18];
  const float* b_hh_b   = (const float*)d_in[19];

  float* ws = (float*)d_ws;
  const size_t SZ_B = (size_t)NBd * H;  // 19,661,100
  const size_t SZ_A = (size_t)NAt * H;  //  4,915,500

  float* ib  = ws;
  float* mb0 = ws + SZ_B;
  float* mb1 = ws + 2 * SZ_B;
  float* ma  = ws + 3 * SZ_B;
  float* xgf     = ib;
  float* message = mb0;
  float* h0      = mb0 + 9831000;
  float* aggb    = mb1;
  float* node    = mb1 + SZ_A;
  float* iat     = mb1 + 2 * SZ_A;
  float* msg     = mb1 + 14745600;
  float* xgb     = mb1;
  float* ah      = ma;

  // pre-split weight region at tail (uint4 granule counts)
  const size_t BASE_FLOATS = 63898800;
  uint4* wsp = (uint4*)(ws + BASE_FLOATS);
  const int G_IA = 5 * 19 * 64;
  const int G_IB = 5 * 19 * 64;
  const int G_WH = 10 * 19 * 64;
  const int G_LR = 29 * 19 * 64;
  const int G_WT = 10 * 57 * 64;
  const int G_WO = 19 * 19 * 64;
  uint4* sp_ia = wsp;
  uint4* sp_ib = sp_ia + 3 * G_IA;
  uint4* sp_wh = sp_ib + 3 * G_IB;
  uint4* sp_lr = sp_wh + 4 * 3 * G_WH;
  uint4* sp_tf = sp_lr + 3 * G_LR;
  uint4* sp_tb = sp_tf + 3 * G_WT;
  uint4* sp_wo = sp_tb + 3 * G_WT;

  dim3 blk(256);
  // all N used here are exact multiples of 19 tiles (300->19, 912->57)
  auto gg3 = [](int M, int NT) {
    return dim3((unsigned)(NT / 19), (unsigned)((M + 63) / 64));
  };
  auto pg = [](int gran) { return dim3((unsigned)((gran + 255) / 256)); };
  const int gA4 = (int)((NAt * 75 + 255) / 256);
  const int gAe = (int)((SZ_A + 255) / 256);

  // ---- weight prep ----
  prep_split_kernel<false><<<pg(G_IA), blk, 0, stream>>>(W_i_atom, sp_ia, 133, 300, 300, 5, 19);
  prep_split_kernel<false><<<pg(G_IB), blk, 0, stream>>>(W_i_bond, sp_ib, 147, 300, 300, 5, 19);
  for (int d = 0; d < 4; d++)
    prep_split_kernel<false><<<pg(G_WH), blk, 0, stream>>>(
        W_h + (size_t)d * H * H, sp_wh + (size_t)d * 3 * G_WH, 300, 300, 300, 10, 19);
  prep_split_kernel<false><<<pg(G_LR), blk, 0, stream>>>(W_lr, sp_lr, 900, 300, 300, 29, 19);
  prep_split_kernel<true><<<pg(G_WT), blk, 0, stream>>>(w_ih_f, sp_tf, 300, 900, 300, 10, 57);
  prep_split_kernel<true><<<pg(G_WT), blk, 0, stream>>>(w_ih_b, sp_tb, 300, 900, 300, 10, 57);
  prep_split_kernel<false><<<pg(G_WO), blk, 0, stream>>>(W_o, sp_wo, 600, 300, 300, 19, 19);

  // ma = relu(f_atoms @ W_i_atom)
  gemm_mfma3<false,false,true,false,false,false,false><<<gg3(NAt, 19), blk, 0, stream>>>(
      f_atoms, nullptr, nullptr, nullptr, nullptr, sp_ia, ma, nullptr, nullptr, nullptr,
      NAt, H, 133, 133, H, 5, 19);
  // ib = relu(f_bonds @ W_i_bond); mb0 = copy
  gemm_mfma3<false,false,true,false,false,true,false><<<gg3(NBd, 19), blk, 0, stream>>>(
      f_bonds, nullptr, nullptr, nullptr, nullptr, sp_ib, ib, mb0, nullptr, nullptr,
      NBd, H, 147, 147, H, 5, 19);

  float* mbp[2] = {mb0, mb1};
  int cur = 0;
  for (int d = 0; d < 4; d++) {
    agg_kernel<true><<<gA4, blk, 0, stream>>>(mbp[cur], a2b, ma);
    gemm_mfma3<true,false,true,true,false,false,true><<<gg3(NBd, 19), blk, 0, stream>>>(
        ma, mbp[cur], nullptr, b2a, b2revb, sp_wh + (size_t)d * 3 * G_WH,
        mbp[1 - cur], nullptr, ib, nullptr, NBd, H, H, H, H, 10, 19);
    cur ^= 1;
  }
  agg_kernel<false><<<gA4, blk, 0, stream>>>(mb0, a2b, aggb);

  gemm_mfma3<false,false,true,false,false,false,false><<<gg3(NAt, 19), blk, 0, stream>>>(
      f_atoms, nullptr, nullptr, nullptr, nullptr, sp_ia, iat, nullptr, nullptr, nullptr,
      NAt, H, 133, 133, H, 5, 19);
  gemm_mfma3<false,false,false,false,true,false,false><<<gg3(NAt, 19), blk, 0, stream>>>(
      aggb, ma, iat, nullptr, nullptr, sp_lr, node, nullptr, nullptr, nullptr,
      NAt, H, 900, H, H, 29, 19);

  h0_kernel<<<(NM * H + 255) / 256, blk, 0, stream>>>(node, h0);
  msg_kernel<<<gAe, blk, 0, stream>>>(node, gru_bias, msg);

  gemm_mfma3<false,true,false,false,false,false,true><<<gg3(16384, 57), blk, 0, stream>>>(
      msg + H, nullptr, nullptr, nullptr, nullptr, sp_tf, xgf, nullptr, nullptr, b_ih_f,
      16384, H3, H, H, H3, 10, 57);
  gemm_mfma3<false,true,false,false,false,false,true><<<gg3(16384, 57), blk, 0, stream>>>(
      msg + H, nullptr, nullptr, nullptr, nullptr, sp_tb, xgb, nullptr, nullptr, b_ih_b,
      16384, H3, H, H, H3, 10, 57);

  // all 65 GRU steps: one launch, 128 independent blocks, no cross-block sync
  gru_fused_kernel<<<dim3(128), blk, 0, stream>>>(
      xgf, xgb, w_hh_f, w_hh_b, b_hh_f, b_hh_b, h0, message);

  row0_kernel<<<3, blk, 0, stream>>>(msg, message);

  gemm_mfma3<false,true,true,false,false,false,true><<<gg3(NAt, 19), blk, 0, stream>>>(
      message, nullptr, nullptr, nullptr, nullptr, sp_wo, ah, nullptr, nullptr, b_o,
      NAt, H, 600, 600, H, 19, 19);
  mean_kernel<<<(NM * H + 255) / 256, blk, 0, stream>>>(ah, (float*)d_out);
}

// Round 9
// 2624.184 us; speedup vs baseline: 1.3747x; 1.3688x over previous
//
#include <hip/hip_runtime.h>
#include <math.h>

#define H 300
#define H3 900
#define NAt 16385
#define NBd 65537
#define NM 256
#define APM 64

typedef __attribute__((ext_vector_type(8))) short bf16x8;
typedef __attribute__((ext_vector_type(4))) float f32x4;

__device__ __forceinline__ unsigned bf16_rne(float x) {
  unsigned u = __float_as_uint(x);
  return (u + 0x7fffu + ((u >> 16) & 1u)) >> 16;
}
__device__ __forceinline__ float bf16_up(unsigned h) {
  return __uint_as_float(h << 16);
}
// 3-way split: x ~= h + m + l (each bf16), residual ~2^-26 |x|
__device__ __forceinline__ void split3(float x, unsigned &h, unsigned &m, unsigned &l) {
  h = bf16_rne(x);
  float r1 = x - bf16_up(h);
  m = bf16_rne(r1);
  float r2 = r1 - bf16_up(m);
  l = bf16_rne(r2);
}
__device__ __forceinline__ void pack8(const unsigned* v, uint4 &o) {
  o.x = v[0] | (v[1] << 16); o.y = v[2] | (v[3] << 16);
  o.z = v[4] | (v[5] << 16); o.w = v[6] | (v[7] << 16);
}

// ======================= weight pre-split =======================
template<bool TRANS>
__global__ __launch_bounds__(256) void prep_split_kernel(
    const float* __restrict__ B, uint4* __restrict__ out,
    int K, int N, int ldb, int KT, int NT)
{
  int g = blockIdx.x * 256 + threadIdx.x;
  int total = KT * NT * 64;
  if (g >= total) return;
  int lane = g & 63;
  int t = (g >> 6) % NT;
  int kt = (g >> 6) / NT;
  int n = t * 16 + (lane & 15);
  int kb = kt * 32 + ((lane >> 4) << 3);
  float x[8];
#pragma unroll
  for (int j = 0; j < 8; j++) {
    int gk = kb + j;
    float v = 0.f;
    if (n < N && gk < K)
      v = TRANS ? B[(size_t)n * ldb + gk] : B[(size_t)gk * ldb + n];
    x[j] = v;
  }
  unsigned h[8], m[8], l[8];
#pragma unroll
  for (int j = 0; j < 8; j++) split3(x[j], h[j], m[j], l[j]);
  uint4 hv, mv, lv;
  pack8(h, hv); pack8(m, mv); pack8(l, lv);
  out[g] = hv;
  out[total + g] = mv;
  out[2 * total + g] = lv;
}

// ======= r18: w_hh transpose (Wt[k][g] = W[g][k]) for coalesced GRU loads =======
__global__ __launch_bounds__(256) void prep_wt_kernel(
    const float* __restrict__ w, float* __restrict__ wt)
{
  int gid = blockIdx.x * 256 + threadIdx.x;
  if (gid >= H * H3) return;
  int k = gid / H3;
  int g = gid - k * H3;
  wt[gid] = w[(size_t)g * H + k];
}

// ============== split-bf16 MFMA GEMM (EXACT r12 — proven) ==============
template<bool ADDMAT, bool BIAS, bool RELU, bool GATHER, bool CONCAT, bool W2, bool VEC>
__global__ __launch_bounds__(256, 2) void gemm_mfma3(
    const float* __restrict__ A, const float* __restrict__ A2,
    const float* __restrict__ A3,
    const int* __restrict__ idx1, const int* __restrict__ idx2,
    const uint4* __restrict__ Bs,
    float* __restrict__ C, float* __restrict__ C2,
    const float* __restrict__ D, const float* __restrict__ bias,
    int M, int N, int K, int lda, int ldc, int KT, int NT)
{
  __shared__ uint4 sA[2][3][256];
  const int tid = threadIdx.x;
  const int lane = tid & 63;
  const int wid = tid >> 6;
  const int m0 = blockIdx.y * 64;
  const int tb = blockIdx.x * 19;
  const bool J5 = (wid < 3);  // wave-uniform: does this wave own a 5th tile?

  const int a_row = m0 + (wid << 4) + (lane & 15);
  const int a_koct = lane >> 4;
  const bool arok = a_row < M;
  const float* Ap = nullptr;
  const float* Ap2 = nullptr;
  const float* Ap3 = nullptr;
  if constexpr (GATHER) {
    int i1 = arok ? idx1[a_row] : 0;
    int i2 = arok ? idx2[a_row] : 0;
    Ap  = A  + (size_t)i1 * lda;
    Ap2 = A2 + (size_t)i2 * lda;
  } else if constexpr (CONCAT) {
    int r = arok ? a_row : 0;
    Ap  = A  + (size_t)r * lda;
    Ap2 = A2 + (size_t)r * lda;
    Ap3 = A3 + (size_t)r * lda;
  } else {
    Ap = A + (size_t)(arok ? a_row : 0) * lda;
  }

  const int PS = KT * NT * 64;  // plane stride (uint4 units)

  f32x4 acc[4][5];
#pragma unroll
  for (int i = 0; i < 4; i++)
#pragma unroll
    for (int j = 0; j < 5; j++) acc[i][j] = (f32x4){0.f, 0.f, 0.f, 0.f};

  float ax[8];
  auto loadA = [&](int kt_) {
    const int gk0 = (kt_ << 5) + (a_koct << 3);
    if constexpr (VEC && !CONCAT) {
      if (arok && gk0 + 8 <= K) {
        float4 p0 = *(const float4*)(Ap + gk0);
        float4 p1 = *(const float4*)(Ap + gk0 + 4);
        if constexpr (GATHER) {
          float4 q0 = *(const float4*)(Ap2 + gk0);
          float4 q1 = *(const float4*)(Ap2 + gk0 + 4);
          ax[0] = p0.x - q0.x; ax[1] = p0.y - q0.y;
          ax[2] = p0.z - q0.z; ax[3] = p0.w - q0.w;
          ax[4] = p1.x - q1.x; ax[5] = p1.y - q1.y;
          ax[6] = p1.z - q1.z; ax[7] = p1.w - q1.w;
        } else {
          ax[0] = p0.x; ax[1] = p0.y; ax[2] = p0.z; ax[3] = p0.w;
          ax[4] = p1.x; ax[5] = p1.y; ax[6] = p1.z; ax[7] = p1.w;
        }
        return;
      }
    }
#pragma unroll
    for (int j = 0; j < 8; j++) {
      int gk = gk0 + j;
      float v = 0.f;
      if (arok && gk < K) {
        if constexpr (GATHER) {
          v = Ap[gk] - Ap2[gk];
        } else if constexpr (CONCAT) {
          int s_ = (gk >= 2 * lda) ? 2 : ((gk >= lda) ? 1 : 0);
          int col = gk - s_ * lda;
          const float* src = (s_ == 0) ? Ap : ((s_ == 1) ? Ap2 : Ap3);
          v = src[col];
        } else {
          v = Ap[gk];
        }
      }
      ax[j] = v;
    }
  };
  auto writeA = [&](int slot) {
    unsigned h[8], m[8], l[8];
#pragma unroll
    for (int j = 0; j < 8; j++) split3(ax[j], h[j], m[j], l[j]);
    uint4 hv, mv, lv;
    pack8(h, hv); pack8(m, mv); pack8(l, lv);
    const int fi = (wid << 6) | lane;
    sA[slot][0][fi] = hv; sA[slot][1][fi] = mv; sA[slot][2][fi] = lv;
  };

  loadA(0);
  writeA(0);
  __syncthreads();

  for (int kt = 0; kt < KT; kt++) {
    const int cur = kt & 1;
    const bool more = kt + 1 < KT;

    const int bk = kt * NT * 64 + tb * 64 + lane;
    bf16x8 breg[5][3];
#pragma unroll
    for (int j = 0; j < 4; j++) {
      const int gidx = bk + (((j << 2) + wid) << 6);
#pragma unroll
      for (int p = 0; p < 3; p++)
        breg[j][p] = ((const bf16x8*)Bs)[gidx + p * PS];
    }
    if (J5) {
      const int gidx = bk + ((16 + wid) << 6);
#pragma unroll
      for (int p = 0; p < 3; p++)
        breg[4][p] = ((const bf16x8*)Bs)[gidx + p * PS];
    }

    if (more) loadA(kt + 1);

    bf16x8 aF[3][4];
#pragma unroll
    for (int p = 0; p < 3; p++)
#pragma unroll
      for (int i = 0; i < 4; i++)
        aF[p][i] = ((const bf16x8*)sA[cur][p])[(i << 6) | lane];

#pragma unroll
    for (int j = 0; j < 5; j++) {
      if (j < 4 || J5) {
#pragma unroll
        for (int i = 0; i < 4; i++) {
          acc[i][j] = __builtin_amdgcn_mfma_f32_16x16x32_bf16(aF[2][i], breg[j][0], acc[i][j], 0, 0, 0);
          acc[i][j] = __builtin_amdgcn_mfma_f32_16x16x32_bf16(aF[0][i], breg[j][2], acc[i][j], 0, 0, 0);
          acc[i][j] = __builtin_amdgcn_mfma_f32_16x16x32_bf16(aF[1][i], breg[j][1], acc[i][j], 0, 0, 0);
          acc[i][j] = __builtin_amdgcn_mfma_f32_16x16x32_bf16(aF[1][i], breg[j][0], acc[i][j], 0, 0, 0);
          acc[i][j] = __builtin_amdgcn_mfma_f32_16x16x32_bf16(aF[0][i], breg[j][1], acc[i][j], 0, 0, 0);
          acc[i][j] = __builtin_amdgcn_mfma_f32_16x16x32_bf16(aF[0][i], breg[j][0], acc[i][j], 0, 0, 0);
        }
      }
    }
    if (more) writeA(cur ^ 1);
    __syncthreads();
  }

  // epilogue: C/D layout col=lane&15, row=(lane>>4)*4+r ; tile t = 4j + wid
  const int cr = (lane >> 4) << 2;
  const int cc = lane & 15;
#pragma unroll
  for (int j = 0; j < 5; j++) {
    if (j == 4 && !J5) break;
    const int t = (j << 2) + wid;
    const int gn = ((tb + t) << 4) + cc;
    if (gn >= N) continue;
#pragma unroll
    for (int i = 0; i < 4; i++) {
#pragma unroll
      for (int r = 0; r < 4; r++) {
        const int gm = m0 + (i << 4) + cr + r;
        if (gm >= M) continue;
        const size_t rowoff = (size_t)gm * ldc;
        float v = acc[i][j][r];
        if constexpr (ADDMAT) v += D[rowoff + gn];
        if constexpr (BIAS) v += bias[gn];
        if constexpr (RELU) v = fmaxf(v, 0.f);
        C[rowoff + gn] = v;
        if constexpr (W2) C2[rowoff + gn] = v;
      }
    }
  }
}

// ============== neighbor aggregation (float4): sum * max over 6 ==============
template<bool UPDATE>
__global__ __launch_bounds__(256) void agg_kernel(
    const float* __restrict__ message_bond, const int* __restrict__ a2b,
    float* __restrict__ out)
{
  int gid = blockIdx.x * 256 + threadIdx.x;
  if (gid >= NAt * 75) return;
  int a = gid / 75;
  int c4 = gid - a * 75;
  const int* ab = a2b + (size_t)a * 6;
  float4 s = {0.f, 0.f, 0.f, 0.f};
  float4 mx = {-3.0e38f, -3.0e38f, -3.0e38f, -3.0e38f};
#pragma unroll
  for (int j = 0; j < 6; j++) {
    float4 v = *(const float4*)(message_bond + (size_t)ab[j] * H + c4 * 4);
    s.x += v.x; s.y += v.y; s.z += v.z; s.w += v.w;
    mx.x = fmaxf(mx.x, v.x); mx.y = fmaxf(mx.y, v.y);
    mx.z = fmaxf(mx.z, v.z); mx.w = fmaxf(mx.w, v.w);
  }
  float4* o = (float4*)(out + (size_t)a * H + c4 * 4);
  float4 r;
  r.x = s.x * mx.x; r.y = s.y * mx.y; r.z = s.z * mx.z; r.w = s.w * mx.w;
  if (UPDATE) {
    float4 c = *o;
    r.x += c.x; r.y += c.y; r.z += c.z; r.w += c.w;
  }
  *o = r;
}

// ======================= misc elementwise =======================
__global__ __launch_bounds__(256) void msg_kernel(
    const float* __restrict__ node, const float* __restrict__ gru_bias,
    float* __restrict__ msg)
{
  int gid = blockIdx.x * 256 + threadIdx.x;
  if (gid >= NAt * H) return;
  int hh = gid % H;
  msg[gid] = fmaxf(node[gid] + gru_bias[hh], 0.f);
}

__global__ __launch_bounds__(256) void h0_kernel(
    const float* __restrict__ node, float* __restrict__ h0)
{
  int gid = blockIdx.x * 256 + threadIdx.x;
  if (gid >= NM * H) return;
  int m = gid / H;
  int hh = gid - m * H;
  const float* base = node + ((size_t)(1 + m * APM)) * H + hh;
  float mx = base[0];
  for (int t = 1; t < APM; t++) mx = fmaxf(mx, base[(size_t)t * H]);
  h0[gid] = mx;
}

__global__ __launch_bounds__(256) void row0_kernel(
    const float* __restrict__ msg, float* __restrict__ message)
{
  int gid = blockIdx.x * 256 + threadIdx.x;
  if (gid >= 2 * H) return;
  message[gid] = msg[gid % H];
}

__global__ __launch_bounds__(256) void mean_kernel(
    const float* __restrict__ ah, float* __restrict__ out)
{
  int gid = blockIdx.x * 256 + threadIdx.x;
  if (gid >= NM * H) return;
  int m = gid / H;
  int hh = gid - m * H;
  const float* base = ah + ((size_t)(1 + m * APM)) * H + hh;
  float s = 0.f;
#pragma unroll 8
  for (int t = 0; t < APM; t++) s += base[(size_t)t * H];
  out[gid] = s * (1.f / APM);
}

// ======================= GRU: block-independent, all 65 steps, ONE launch =======================
// r18 = r17 structure (128 independent blocks: 2 dir x 64 groups of 4 mols,
// __syncthreads only, no fences, passed refcheck) with the two r17 memory
// pathologies fixed:
//  (a) W loads COALESCED: w_hh pre-transposed to Wt[k][g]; thread t owns
//      gate g=tid, so lane-consecutive addresses. (r17: stride-1200B.)
//  (b) 1024 threads (16 waves -> 4/SIMD) for latency hiding. (r17: 1/SIMD.)
// Per-gate FP chunk order (12-product left-to-right sums) verbatim from the
// r9/r12/r17 kernels -> identical output.
__global__ __launch_bounds__(1024) void gru_fused_kernel(
    const float* __restrict__ xg_f, const float* __restrict__ xg_b,
    const float* __restrict__ wt_f, const float* __restrict__ wt_b,
    const float* __restrict__ b_hh_f, const float* __restrict__ b_hh_b,
    const float* __restrict__ h0,
    float* __restrict__ message) // [NAt][600]
{
  __shared__ __attribute__((aligned(16))) float h_lds[2][4 * H];
  __shared__ __attribute__((aligned(16))) float g_lds[4 * H3];
  const int tid = threadIdx.x;
  const int b = blockIdx.x;
  const int mg = b & 63;
  const int dir = b >> 6;
  const int mol0 = mg * 4;
  const float* xg = dir ? xg_b : xg_f;
  const float* wt = dir ? wt_b : wt_f;   // [300][900]
  const float* bhh = dir ? b_hh_b : b_hh_f;

  for (int s = 0; s <= 64; s++) {
    float* hl_w = h_lds[s & 1];
    const float* hl_r = h_lds[(s ^ 1) & 1];
    int t_prev = 0;
    if (s > 0) t_prev = dir ? (64 - s) : (s - 1);

    // phase 1: h(s) for this block's 4 mols; write message row for t_prev
    for (int i = tid; i < 4 * H; i += 1024) {
      int m = i / H;
      int hh = i - m * H;
      int mol = mol0 + m;
      float hc;
      if (s == 0) {
        hc = h0[(size_t)mol * H + hh];
      } else {
        const float* xr = xg + ((size_t)(mol * 64 + t_prev)) * H3;
        float ir = xr[hh], iz = xr[H + hh], inn = xr[2 * H + hh];
        const float* gp = g_lds + m * H3;
        float hr = gp[hh], hz = gp[H + hh], hn = gp[2 * H + hh];
        float hp = hl_r[i];
        float rr = 1.f / (1.f + expf(-(ir + hr)));
        float zz = 1.f / (1.f + expf(-(iz + hz)));
        float nn = tanhf(inn + rr * hn);
        hc = (1.f - zz) * nn + zz * hp;
      }
      hl_w[i] = hc;
      if (s > 0) {
        int row = 1 + mol * 64 + t_prev;
        message[(size_t)row * 600 + dir * H + hh] = hc;
      }
    }
    __syncthreads();
    if (s == 64) break;

    // phase 2: thread t (<900) owns gate g=t; 4 mol-accs; coalesced Wt loads.
    if (tid < 900) {
      const int g = tid;
      float acc[4] = {0.f, 0.f, 0.f, 0.f};
      for (int c = 0; c < 25; c++) {
        const int fb = c * 12;
        float w[12];
#pragma unroll
        for (int i = 0; i < 12; i++)
          w[i] = wt[(size_t)(fb + i) * H3 + g];
#pragma unroll
        for (int m = 0; m < 4; m++) {
          const float4* hm = (const float4*)(hl_w + m * H);
          float4 a0 = hm[c * 3];
          float4 a1 = hm[c * 3 + 1];
          float4 a2 = hm[c * 3 + 2];
          acc[m] += w[0] * a0.x + w[1] * a0.y + w[2] * a0.z + w[3] * a0.w
                  + w[4] * a1.x + w[5] * a1.y + w[6] * a1.z + w[7] * a1.w
                  + w[8] * a2.x + w[9] * a2.y + w[10] * a2.z + w[11] * a2.w;
        }
      }
      const float bb = bhh[g];
#pragma unroll
      for (int m = 0; m < 4; m++)
        g_lds[m * H3 + g] = acc[m] + bb;
    }
    __syncthreads();
  }
}

// ======================= host =======================
// Base layout 63,898,800 floats = 255.6 MB + pre-split weights 9.2 MB
// + transposed w_hh 2.16 MB at tail.
extern "C" void kernel_launch(void* const* d_in, const int* in_sizes, int n_in,
                              void* d_out, int out_size, void* d_ws, size_t ws_size,
                              hipStream_t stream) {
  (void)in_sizes; (void)n_in; (void)out_size; (void)ws_size;
  const float* f_atoms  = (const float*)d_in[0];
  const float* f_bonds  = (const float*)d_in[1];
  const int*   a2b      = (const int*)d_in[2];
  const int*   b2a      = (const int*)d_in[3];
  const int*   b2revb   = (const int*)d_in[4];
  const float* W_i_atom = (const float*)d_in[5];
  const float* W_i_bond = (const float*)d_in[6];
  const float* W_h      = (const float*)d_in[7];
  const float* W_lr     = (const float*)d_in[8];
  const float* W_o      = (const float*)d_in[9];
  const float* b_o      = (const float*)d_in[10];
  const float* gru_bias = (const float*)d_in[11];
  const float* w_ih_f   = (const float*)d_in[12];
  const float* w_hh_f   = (const float*)d_in[13];
  const float* b_ih_f   = (const float*)d_in[14];
  const float* b_hh_f   = (const float*)d_in[15];
  const float* w_ih_b   = (const float*)d_in[16];
  const float* w_hh_b   = (const float*)d_in[17];
  const float* b_ih_b   = (const float*)d_in[18];
  const float* b_hh_b   = (const float*)d_in[19];

  float* ws = (float*)d_ws;
  const size_t SZ_B = (size_t)NBd * H;  // 19,661,100
  const size_t SZ_A = (size_t)NAt * H;  //  4,915,500

  float* ib  = ws;
  float* mb0 = ws + SZ_B;
  float* mb1 = ws + 2 * SZ_B;
  float* ma  = ws + 3 * SZ_B;
  float* xgf     = ib;
  float* message = mb0;
  float* h0      = mb0 + 9831000;
  float* aggb    = mb1;
  float* node    = mb1 + SZ_A;
  float* iat     = mb1 + 2 * SZ_A;
  float* msg     = mb1 + 14745600;
  float* xgb     = mb1;
  float* ah      = ma;

  // pre-split weight region at tail (uint4 granule counts)
  const size_t BASE_FLOATS = 63898800;
  uint4* wsp = (uint4*)(ws + BASE_FLOATS);
  const int G_IA = 5 * 19 * 64;
  const int G_IB = 5 * 19 * 64;
  const int G_WH = 10 * 19 * 64;
  const int G_LR = 29 * 19 * 64;
  const int G_WT = 10 * 57 * 64;
  const int G_WO = 19 * 19 * 64;
  uint4* sp_ia = wsp;
  uint4* sp_ib = sp_ia + 3 * G_IA;
  uint4* sp_wh = sp_ib + 3 * G_IB;
  uint4* sp_lr = sp_wh + 4 * 3 * G_WH;
  uint4* sp_tf = sp_lr + 3 * G_LR;
  uint4* sp_tb = sp_tf + 3 * G_WT;
  uint4* sp_wo = sp_tb + 3 * G_WT;
  // transposed w_hh (float) after the split region
  float* wt_f = (float*)(sp_wo + 3 * G_WO);
  float* wt_b = wt_f + (size_t)H * H3;

  dim3 blk(256);
  // all N used here are exact multiples of 19 tiles (300->19, 912->57)
  auto gg3 = [](int M, int NT) {
    return dim3((unsigned)(NT / 19), (unsigned)((M + 63) / 64));
  };
  auto pg = [](int gran) { return dim3((unsigned)((gran + 255) / 256)); };
  const int gA4 = (int)((NAt * 75 + 255) / 256);
  const int gAe = (int)((SZ_A + 255) / 256);
  const int gWT = (int)((H * H3 + 255) / 256);

  // ---- weight prep ----
  prep_split_kernel<false><<<pg(G_IA), blk, 0, stream>>>(W_i_atom, sp_ia, 133, 300, 300, 5, 19);
  prep_split_kernel<false><<<pg(G_IB), blk, 0, stream>>>(W_i_bond, sp_ib, 147, 300, 300, 5, 19);
  for (int d = 0; d < 4; d++)
    prep_split_kernel<false><<<pg(G_WH), blk, 0, stream>>>(
        W_h + (size_t)d * H * H, sp_wh + (size_t)d * 3 * G_WH, 300, 300, 300, 10, 19);
  prep_split_kernel<false><<<pg(G_LR), blk, 0, stream>>>(W_lr, sp_lr, 900, 300, 300, 29, 19);
  prep_split_kernel<true><<<pg(G_WT), blk, 0, stream>>>(w_ih_f, sp_tf, 300, 900, 300, 10, 57);
  prep_split_kernel<true><<<pg(G_WT), blk, 0, stream>>>(w_ih_b, sp_tb, 300, 900, 300, 10, 57);
  prep_split_kernel<false><<<pg(G_WO), blk, 0, stream>>>(W_o, sp_wo, 600, 300, 300, 19, 19);
  prep_wt_kernel<<<gWT, blk, 0, stream>>>(w_hh_f, wt_f);
  prep_wt_kernel<<<gWT, blk, 0, stream>>>(w_hh_b, wt_b);

  // ma = relu(f_atoms @ W_i_atom)
  gemm_mfma3<false,false,true,false,false,false,false><<<gg3(NAt, 19), blk, 0, stream>>>(
      f_atoms, nullptr, nullptr, nullptr, nullptr, sp_ia, ma, nullptr, nullptr, nullptr,
      NAt, H, 133, 133, H, 5, 19);
  // ib = relu(f_bonds @ W_i_bond); mb0 = copy
  gemm_mfma3<false,false,true,false,false,true,false><<<gg3(NBd, 19), blk, 0, stream>>>(
      f_bonds, nullptr, nullptr, nullptr, nullptr, sp_ib, ib, mb0, nullptr, nullptr,
      NBd, H, 147, 147, H, 5, 19);

  float* mbp[2] = {mb0, mb1};
  int cur = 0;
  for (int d = 0; d < 4; d++) {
    agg_kernel<true><<<gA4, blk, 0, stream>>>(mbp[cur], a2b, ma);
    gemm_mfma3<true,false,true,true,false,false,true><<<gg3(NBd, 19), blk, 0, stream>>>(
        ma, mbp[cur], nullptr, b2a, b2revb, sp_wh + (size_t)d * 3 * G_WH,
        mbp[1 - cur], nullptr, ib, nullptr, NBd, H, H, H, H, 10, 19);
    cur ^= 1;
  }
  agg_kernel<false><<<gA4, blk, 0, stream>>>(mb0, a2b, aggb);

  gemm_mfma3<false,false,true,false,false,false,false><<<gg3(NAt, 19), blk, 0, stream>>>(
      f_atoms, nullptr, nullptr, nullptr, nullptr, sp_ia, iat, nullptr, nullptr, nullptr,
      NAt, H, 133, 133, H, 5, 19);
  gemm_mfma3<false,false,false,false,true,false,false><<<gg3(NAt, 19), blk, 0, stream>>>(
      aggb, ma, iat, nullptr, nullptr, sp_lr, node, nullptr, nullptr, nullptr,
      NAt, H, 900, H, H, 29, 19);

  h0_kernel<<<(NM * H + 255) / 256, blk, 0, stream>>>(node, h0);
  msg_kernel<<<gAe, blk, 0, stream>>>(node, gru_bias, msg);

  gemm_mfma3<false,true,false,false,false,false,true><<<gg3(16384, 57), blk, 0, stream>>>(
      msg + H, nullptr, nullptr, nullptr, nullptr, sp_tf, xgf, nullptr, nullptr, b_ih_f,
      16384, H3, H, H, H3, 10, 57);
  gemm_mfma3<false,true,false,false,false,false,true><<<gg3(16384, 57), blk, 0, stream>>>(
      msg + H, nullptr, nullptr, nullptr, nullptr, sp_tb, xgb, nullptr, nullptr, b_ih_b,
      16384, H3, H, H, H3, 10, 57);

  // all 65 GRU steps: one launch, 128 independent blocks, no cross-block sync
  gru_fused_kernel<<<dim3(128), dim3(1024), 0, stream>>>(
      xgf, xgb, wt_f, wt_b, b_hh_f, b_hh_b, h0, message);

  row0_kernel<<<3, blk, 0, stream>>>(msg, message);

  gemm_mfma3<false,true,true,false,false,false,true><<<gg3(NAt, 19), blk, 0, stream>>>(
      message, nullptr, nullptr, nullptr, nullptr, sp_wo, ah, nullptr, nullptr, b_o,
      NAt, H, 600, 600, H, 19, 19);
  mean_kernel<<<(NM * H + 255) / 256, blk, 0, stream>>>(ah, (float*)d_out);
}